// Round 6
// baseline (161.079 us; speedup 1.0000x reference)
//
#include <hip/hip_runtime.h>

// ChebyshevAdditiveAngularMargin — HBM-bound elementwise op.
//   cosine = clip(outputs, -1+1e-7, 1-1e-7)
//   phi    = clenshaw(cosine, coeffs)            (Chebyshev, degree 30)
//   phi    = cosine > TH ? phi : cosine - MM
//   out    = 30 * (targets*phi + (1-targets)*cosine)   (targets one-hot)
//
// Traffic: outputs 256MB (HBM) + targets 256MB (L3-resident, measured) +
// write 256MB (HBM). Ladder: R1 grid-stride 162us -> R4 one-shot 4x
// float4/thread 145us -> R5 8x/thread 149us (occupancy drop, reverted).
// R6: persistent blocks + double-buffered register prefetch. One-shot waves
// drain all loads before compute and retire (wave-churn bubble per block);
// here 8 loads for tile k+1 stay in flight under tile k's compute+store,
// continuously, with zero wave churn. 2048 blocks, each owns a contiguous
// 128KB window per array, 8 pipelined iterations of 16KB tiles.

namespace {

typedef float f32x4 __attribute__((ext_vector_type(4)));

constexpr float kClipLo = -0.9999999f;   // -1 + 1e-7 rounded to f32
constexpr float kClipHi =  0.9999999f;   //  1 - 1e-7 rounded to f32
constexpr float kTH     = -0.98006657784124163f;  // cos(pi - 0.2)
constexpr float kMM     =  0.039733866159012243f; // sin(pi - 0.2) * 0.2
constexpr float kSCALE  = 30.0f;
constexpr int   kDegree = 30;            // 31 coefficients

constexpr int kBlock   = 256;
constexpr int kVecs    = 4;   // float4 per thread per tile
constexpr int kIters   = 8;   // tiles per block
constexpr int kTile    = kBlock * kVecs;          // 1024 float4 per tile
constexpr int kPerBlk  = kTile * kIters;          // 8192 float4 per block

__device__ __forceinline__ float clenshaw_phi(float x, const float* __restrict__ coeffs) {
    // b_k = c_k + 2x*b_{k+1} - b_{k+2}, k = DEGREE..0;  f(x) = b_0 - x*b_1
    const float x2 = 2.0f * x;
    float b1 = 0.0f, b2 = 0.0f;
#pragma unroll
    for (int k = kDegree; k >= 0; --k) {
        float b = coeffs[k] + x2 * b1 - b2;
        b2 = b1;
        b1 = b;
    }
    return b1 - b2 * x;
}

__device__ __forceinline__ f32x4 process4(f32x4 o, f32x4 t,
                                          const float* __restrict__ coeffs) {
    f32x4 r;
#pragma unroll
    for (int j = 0; j < 4; ++j) {
        const float x = fminf(fmaxf(o[j], kClipLo), kClipHi);
        float rv = x;  // targets == 0 path: out = cosine
        if (t[j] != 0.0f) {
            // rare path: ~1 element per 8192
            const float phi = (x > kTH) ? clenshaw_phi(x, coeffs) : (x - kMM);
            rv = t[j] * phi + (1.0f - t[j]) * x;
        }
        r[j] = kSCALE * rv;
    }
    return r;
}

#define LOAD_TILE(BUF, IT)                                                  \
    do {                                                                    \
        const int _b = base + (IT) * kTile;                                 \
        _Pragma("unroll")                                                   \
        for (int u = 0; u < kVecs; ++u) {                                   \
            o##BUF[u] = outputs4[_b + kBlock * u];                          \
            t##BUF[u] = targets4[_b + kBlock * u];                          \
        }                                                                   \
    } while (0)

#define STORE_TILE(BUF, IT)                                                 \
    do {                                                                    \
        const int _b = base + (IT) * kTile;                                 \
        _Pragma("unroll")                                                   \
        for (int u = 0; u < kVecs; ++u) {                                   \
            dst4[_b + kBlock * u] = process4(o##BUF[u], t##BUF[u], coeffs); \
        }                                                                   \
    } while (0)

__global__ __launch_bounds__(256) void cheb_aam_kernel(
    const f32x4* __restrict__ outputs4,
    const f32x4* __restrict__ targets4,
    const float* __restrict__ coeffs,
    f32x4*       __restrict__ dst4,
    int n4) {
    const int base = blockIdx.x * kPerBlk + threadIdx.x;

    if (blockIdx.x * kPerBlk + kPerBlk <= n4) {
        // Fast path: full window, software-pipelined double buffer.
        f32x4 oA[kVecs], tA[kVecs], oB[kVecs], tB[kVecs];
        LOAD_TILE(A, 0);
#pragma unroll
        for (int it = 0; it < kIters; it += 2) {
            LOAD_TILE(B, it + 1);        // prefetch under A's compute
            STORE_TILE(A, it);
            if (it + 2 < kIters) LOAD_TILE(A, it + 2);  // prefetch under B
            STORE_TILE(B, it + 1);
        }
    } else {
        // Tail window (not taken when kPerBlk divides n4).
        for (int it = 0; it < kIters; ++it) {
#pragma unroll
            for (int u = 0; u < kVecs; ++u) {
                const int i = base + it * kTile + kBlock * u;
                if (i < n4) dst4[i] = process4(outputs4[i], targets4[i], coeffs);
            }
        }
    }
}

}  // namespace

extern "C" void kernel_launch(void* const* d_in, const int* in_sizes, int n_in,
                              void* d_out, int out_size, void* d_ws, size_t ws_size,
                              hipStream_t stream) {
    const float* outputs = (const float*)d_in[0];
    const float* targets = (const float*)d_in[1];
    const float* coeffs  = (const float*)d_in[2];
    float* dst = (float*)d_out;

    const int n  = out_size;       // 8192*8192, divisible by 4
    const int n4 = n / 4;

    const int grid = (n4 + kPerBlk - 1) / kPerBlk;   // 2048 for 8192^2

    cheb_aam_kernel<<<grid, kBlock, 0, stream>>>(
        (const f32x4*)outputs, (const f32x4*)targets, coeffs,
        (f32x4*)dst, n4);
}

// Round 7
// 115.327 us; speedup vs baseline: 1.3967x; 1.3967x over previous
//
#include <hip/hip_runtime.h>

// ChebyshevAdditiveAngularMargin — HBM-bound elementwise op.
//   cosine = clip(outputs, -1+1e-7, 1-1e-7)
//   phi    = clenshaw(cosine, coeffs)            (Chebyshev, degree 30)
//   phi    = cosine > TH ? phi : cosine - MM
//   out    = 30 * (targets*phi + (1-targets)*cosine)   (targets one-hot)
//
// Traffic: outputs 256MB (HBM) + targets 256MB (L3-resident, measured) +
// write 256MB (HBM). Ladder: R1 grid-stride 162 -> R4 one-shot 4xfloat4
// batched 145 -> R5 8x/thread 149 (occupancy drop) -> R6 persistent dbuf 161
// (occupancy 47%). R7: back to R4 structure + nontemporal hints on the two
// zero-reuse streams (outputs load, dst store). targets is exactly L3-sized
// (256MB); NT keeps the streaming pair from thrashing it out of the
// Infinity Cache.

namespace {

typedef float f32x4 __attribute__((ext_vector_type(4)));

constexpr float kClipLo = -0.9999999f;   // -1 + 1e-7 rounded to f32
constexpr float kClipHi =  0.9999999f;   //  1 - 1e-7 rounded to f32
constexpr float kTH     = -0.98006657784124163f;  // cos(pi - 0.2)
constexpr float kMM     =  0.039733866159012243f; // sin(pi - 0.2) * 0.2
constexpr float kSCALE  = 30.0f;
constexpr int   kDegree = 30;            // 31 coefficients
constexpr int   kPerThread = 4;          // float4s per thread per array

__device__ __forceinline__ float clenshaw_phi(float x, const float* __restrict__ coeffs) {
    // b_k = c_k + 2x*b_{k+1} - b_{k+2}, k = DEGREE..0;  f(x) = b_0 - x*b_1
    const float x2 = 2.0f * x;
    float b1 = 0.0f, b2 = 0.0f;
#pragma unroll
    for (int k = kDegree; k >= 0; --k) {
        float b = coeffs[k] + x2 * b1 - b2;
        b2 = b1;
        b1 = b;
    }
    return b1 - b2 * x;
}

__device__ __forceinline__ f32x4 process4(f32x4 o, f32x4 t,
                                          const float* __restrict__ coeffs) {
    f32x4 r;
#pragma unroll
    for (int j = 0; j < 4; ++j) {
        const float x = fminf(fmaxf(o[j], kClipLo), kClipHi);
        float rv = x;  // targets == 0 path: out = cosine
        if (t[j] != 0.0f) {
            // rare path: ~1 element per 8192
            const float phi = (x > kTH) ? clenshaw_phi(x, coeffs) : (x - kMM);
            rv = t[j] * phi + (1.0f - t[j]) * x;
        }
        r[j] = kSCALE * rv;
    }
    return r;
}

// One shot per thread: kPerThread coalesced float4 per array, stride-256
// within the block. All loads issued before any use. outputs/dst are
// nontemporal (zero reuse); targets cached (L3-resident across replays).
__global__ __launch_bounds__(256) void cheb_aam_kernel(
    const f32x4* __restrict__ outputs4,
    const f32x4* __restrict__ targets4,
    const float* __restrict__ coeffs,
    f32x4*       __restrict__ dst4,
    int n4) {
    const int base = blockIdx.x * (256 * kPerThread) + threadIdx.x;

    if (base + 256 * (kPerThread - 1) < n4) {  // uniform fast path
        f32x4 o[kPerThread], t[kPerThread];
#pragma unroll
        for (int u = 0; u < kPerThread; ++u)
            o[u] = __builtin_nontemporal_load(&outputs4[base + 256 * u]);
#pragma unroll
        for (int u = 0; u < kPerThread; ++u)
            t[u] = targets4[base + 256 * u];
#pragma unroll
        for (int u = 0; u < kPerThread; ++u) {
            f32x4 r = process4(o[u], t[u], coeffs);
            __builtin_nontemporal_store(r, &dst4[base + 256 * u]);
        }
    } else {  // tail block (not taken for 8192x8192)
#pragma unroll
        for (int u = 0; u < kPerThread; ++u) {
            const int i = base + 256 * u;
            if (i < n4) {
                f32x4 r = process4(__builtin_nontemporal_load(&outputs4[i]),
                                   targets4[i], coeffs);
                __builtin_nontemporal_store(r, &dst4[i]);
            }
        }
    }
}

}  // namespace

extern "C" void kernel_launch(void* const* d_in, const int* in_sizes, int n_in,
                              void* d_out, int out_size, void* d_ws, size_t ws_size,
                              hipStream_t stream) {
    const float* outputs = (const float*)d_in[0];
    const float* targets = (const float*)d_in[1];
    const float* coeffs  = (const float*)d_in[2];
    float* dst = (float*)d_out;

    const int n  = out_size;       // 8192*8192, divisible by 4
    const int n4 = n / 4;

    const int block = 256;
    const int perBlock = block * kPerThread;           // 1024 float4 / block
    const int grid = (n4 + perBlock - 1) / perBlock;   // 16384 for 8192^2

    cheb_aam_kernel<<<grid, block, 0, stream>>>(
        (const f32x4*)outputs, (const f32x4*)targets, coeffs,
        (f32x4*)dst, n4);
}